// Round 1
// baseline (83.474 us; speedup 1.0000x reference)
//
#include <hip/hip_runtime.h>
#include <hip/hip_bf16.h>

// GMM log-likelihood, N=65536 pts, K=32 comps, F=128 feats.
// Strategy: D[g,n] = sum_f Pt[k][g][f]*x[n][f] + (-mu@P)[g]*1 via bf16 MFMA
// (32x32x16), K padded 128->144 for the mean fold. Row-sum of squares is
// in-lane + one shfl_xor(32); online logsumexp over k.

#define NPTS 65536
#define KC 32
#define FD 128
#define ROWB 288           // bytes per g-row in A image (144 bf16)
#define SLAB (128 * ROWB)  // 36864 bytes per component
#define LDSB0 0
#define LDSB1 SLAB
#define LDSCK (2 * SLAB)   // 73728: 32 floats of ck2
#define LDSTOT (2 * SLAB + 128)

typedef __attribute__((ext_vector_type(8))) short short8;
typedef __attribute__((ext_vector_type(8))) unsigned short ushort8;
typedef __attribute__((ext_vector_type(16))) float f32x16;

static __device__ __forceinline__ unsigned short f2bf(float f) {
  unsigned int u = __float_as_uint(f);
  u += 0x7FFFu + ((u >> 16) & 1u);  // RNE
  return (unsigned short)(u >> 16);
}

// --- prep 1: mproj[k][g] = sum_f means[k][f] * P[k][f][g];  ck2[k] ---
__global__ void prep_mproj(const float* __restrict__ means, const float* __restrict__ P,
                           const float* __restrict__ w, float* __restrict__ mproj,
                           float* __restrict__ ck2) {
  int k = blockIdx.x, g = threadIdx.x;  // 32 blocks x 128 threads
  const float* Pk = P + k * FD * FD;
  float acc = 0.f;
  for (int f = 0; f < FD; ++f) acc = fmaf(means[k * FD + f], Pk[f * FD + g], acc);
  mproj[k * FD + g] = acc;
  __shared__ float red[FD];
  red[g] = logf(Pk[g * FD + g]);  // diag > 0
  __syncthreads();
  for (int off = 64; off; off >>= 1) {
    if (g < off) red[g] += red[g + off];
    __syncthreads();
  }
  // ck2 = log w + logdet - 0.5*F*log(2*pi)
  if (g == 0) ck2[k] = logf(w[k]) + red[0] - 0.5f * (float)FD * 1.8378770664093453f;
}

// --- prep 2: build bf16 swizzled A image.
// Logical: A[k][g][f] = P[k][f][g] for f<128; f==128 -> -mproj[k][g]; else 0.
// Image byte layout per k: row g = 288B = 18 chunks of 16B.
// Data chunks c in 0..15 stored at position c ^ (g&7); chunks 16,17 linear.
__global__ void prep_A(const float* __restrict__ P, const float* __restrict__ mproj,
                       unsigned char* __restrict__ Aimg) {
  int id = blockIdx.x * blockDim.x + threadIdx.x;  // 0 .. 73727 (chunk id)
  int c = id % 18;
  int gk = id / 18;
  int g = gk & 127;
  int k = gk >> 7;
  ushort8 v;
#pragma unroll
  for (int i = 0; i < 8; ++i) v[i] = 0;
  if (c < 16) {
#pragma unroll
    for (int i = 0; i < 8; ++i) v[i] = f2bf(P[k * 16384 + (c * 8 + i) * 128 + g]);
  } else if (c == 16) {
    v[0] = f2bf(-mproj[k * 128 + g]);
  }
  int cp = (c < 16) ? (c ^ (g & 7)) : c;
  *(ushort8*)(Aimg + (size_t)k * SLAB + g * ROWB + cp * 16) = v;
}

// --- main ---
template <int RBUF, int WBUF>
__device__ __forceinline__ void comp_body(int k, const unsigned char* __restrict__ Aimg,
                                          unsigned char* smem, int wid, int lane,
                                          const int* asr, const short8* xf, float& m,
                                          float& ssum) {
  // stage next component's A slab into WBUF (wave-uniform LDS base + lane*16)
  if (k + 1 < KC) {
    const unsigned char* gs = Aimg + (size_t)(k + 1) * SLAB + wid * 9216 + lane * 16;
    unsigned char* ls = smem + WBUF + wid * 9216;
#pragma unroll
    for (int i = 0; i < 9; ++i)
      __builtin_amdgcn_global_load_lds(
          (const __attribute__((address_space(1))) void*)(gs + i * 1024),
          (__attribute__((address_space(3))) void*)(ls + i * 1024), 16, 0, 0);
  }
  float sp0 = 0.f, sp1 = 0.f, sp2 = 0.f, sp3 = 0.f;
#pragma unroll
  for (int gt = 0; gt < 4; ++gt) {
    f32x16 d;
#pragma unroll
    for (int i = 0; i < 16; ++i) d[i] = 0.f;
#pragma unroll
    for (int s = 0; s < 9; ++s) {
      const short8 a = *(const short8*)(smem + RBUF + gt * 9216 + asr[s]);
      d = __builtin_amdgcn_mfma_f32_32x32x16_bf16(a, xf[s], d, 0, 0, 0);
    }
#pragma unroll
    for (int i = 0; i < 16; ++i) {
      float t = d[i];
      if ((i & 3) == 0) sp0 = fmaf(t, t, sp0);
      else if ((i & 3) == 1) sp1 = fmaf(t, t, sp1);
      else if ((i & 3) == 2) sp2 = fmaf(t, t, sp2);
      else sp3 = fmaf(t, t, sp3);
    }
  }
  float tot = (sp0 + sp1) + (sp2 + sp3);  // 64 of 128 g-rows (this half)
  tot += __shfl_xor(tot, 32, 64);         // + other half -> full Mahalanobis^2
  float cv = ((const float*)(smem + LDSCK))[k];
  float v = cv - 0.5f * tot;
  float nm = fmaxf(m, v);
  ssum = ssum * __expf(m - nm) + __expf(v - nm);
  m = nm;
  asm volatile("s_waitcnt vmcnt(0)" ::: "memory");
  __syncthreads();
}

__global__ __launch_bounds__(256, 2) void gmm_main(const float* __restrict__ x,
                                                   const unsigned char* __restrict__ Aimg,
                                                   const float* __restrict__ ck2,
                                                   float* __restrict__ out) {
  __shared__ __align__(16) unsigned char smem[LDSTOT];
  const int tid = threadIdx.x;
  const int wid = tid >> 6;
  const int lane = tid & 63;
  const int half = lane >> 5;
  const int ln = lane & 31;
  const int nb = blockIdx.x * 4 + wid;  // 32-row block per wave
  const int row = nb * 32 + ln;

  if (tid < KC) ((float*)(smem + LDSCK))[tid] = ck2[tid];

  // stage component 0 into BUF0
  {
    const unsigned char* gs = Aimg + wid * 9216 + lane * 16;
    unsigned char* ls = smem + LDSB0 + wid * 9216;
#pragma unroll
    for (int i = 0; i < 9; ++i)
      __builtin_amdgcn_global_load_lds(
          (const __attribute__((address_space(1))) void*)(gs + i * 1024),
          (__attribute__((address_space(3))) void*)(ls + i * 1024), 16, 0, 0);
  }

  // B fragments: x rows in registers for the whole kernel.
  // frag s, lane: x[row][s*16 + half*8 + i], i=0..7
  short8 xf[9];
  const float* xrow = x + (size_t)row * FD;
#pragma unroll
  for (int s = 0; s < 8; ++s) {
    const float4 a = *(const float4*)(xrow + s * 16 + half * 8);
    const float4 b = *(const float4*)(xrow + s * 16 + half * 8 + 4);
    short8 f;
    f[0] = (short)f2bf(a.x); f[1] = (short)f2bf(a.y);
    f[2] = (short)f2bf(a.z); f[3] = (short)f2bf(a.w);
    f[4] = (short)f2bf(b.x); f[5] = (short)f2bf(b.y);
    f[6] = (short)f2bf(b.z); f[7] = (short)f2bf(b.w);
    xf[s] = f;
  }
  {  // k-step 8: B[128][n] = 1 (mean fold), rest 0
    short8 f;
#pragma unroll
    for (int i = 0; i < 8; ++i) f[i] = 0;
    if (half == 0) f[0] = (short)0x3F80;  // bf16(1.0)
    xf[8] = f;
  }

  // per-lane LDS read offsets (A frags): g = gt*32 + ln, chunk c0 = 2s+half,
  // stored at c0 ^ (g&7); g&7 == ln&7.
  int asr[9];
#pragma unroll
  for (int s = 0; s < 8; ++s) asr[s] = ln * ROWB + (((2 * s + half) ^ (ln & 7)) << 4);
  asr[8] = ln * ROWB + 256 + half * 16;

  asm volatile("s_waitcnt vmcnt(0)" ::: "memory");
  __syncthreads();

  float m = -__builtin_inff(), ssum = 0.f;
  for (int k2 = 0; k2 < KC; k2 += 2) {
    comp_body<LDSB0, LDSB1>(k2, Aimg, smem, wid, lane, asr, xf, m, ssum);
    comp_body<LDSB1, LDSB0>(k2 + 1, Aimg, smem, wid, lane, asr, xf, m, ssum);
  }
  if (half == 0) out[row] = m + logf(ssum);
}

extern "C" void kernel_launch(void* const* d_in, const int* in_sizes, int n_in,
                              void* d_out, int out_size, void* d_ws, size_t ws_size,
                              hipStream_t stream) {
  const float* x = (const float*)d_in[0];
  const float* means = (const float*)d_in[1];
  const float* P = (const float*)d_in[2];
  const float* w = (const float*)d_in[3];
  float* out = (float*)d_out;

  unsigned char* ws = (unsigned char*)d_ws;
  unsigned char* Aimg = ws;                             // 32*36864 = 1179648 B
  float* mproj = (float*)(ws + 1179648);                // 16384 B
  float* ck2 = (float*)(ws + 1179648 + 16384);          // 128 B

  prep_mproj<<<32, 128, 0, stream>>>(means, P, w, mproj, ck2);
  prep_A<<<288, 256, 0, stream>>>(P, mproj, Aimg);      // 288*256 = 73728 chunks
  gmm_main<<<NPTS / 128, 256, 0, stream>>>(x, Aimg, ck2, out);
}